// Round 3
// baseline (307.775 us; speedup 1.0000x reference)
//
#include <hip/hip_runtime.h>

typedef short  short4v __attribute__((ext_vector_type(4)));
typedef short  short8v __attribute__((ext_vector_type(8)));
typedef __bf16 bf16x8  __attribute__((ext_vector_type(8)));
typedef float  f32x4   __attribute__((ext_vector_type(4)));
typedef float  float4v __attribute__((ext_vector_type(4)));

__device__ __forceinline__ short f2bf(float f) {
  unsigned u = __builtin_bit_cast(unsigned, f);
  u += 0x7fffu + ((u >> 16) & 1u);   // RNE
  return (short)(u >> 16);
}
__device__ __forceinline__ float bf2f(short h) {
  unsigned u = ((unsigned)(unsigned short)h) << 16;
  return __builtin_bit_cast(float, u);
}
__device__ __forceinline__ bf16x8 ld8(const short* p) {
  return __builtin_bit_cast(bf16x8, *reinterpret_cast<const short8v*>(p));
}

// ---------- fp32 -> bf16 convert (vectorized, n4 = n/4 groups) ----------
__global__ __launch_bounds__(256) void k_cvt(const float* __restrict__ in,
                                             short* __restrict__ out, int n4) {
  int i = blockIdx.x * 256 + threadIdx.x;
  if (i >= n4) return;
  float4v v = *reinterpret_cast<const float4v*>(in + (long)i * 4);
  short4v o;
  o[0] = f2bf(v[0]); o[1] = f2bf(v[1]); o[2] = f2bf(v[2]); o[3] = f2bf(v[3]);
  *reinterpret_cast<short4v*>(out + (long)i * 4) = o;
}

// ---------- 256x256 8-phase GEMM: C[M,N] = A[M,K]*B[N,K]^T (+bias) ----------
// 512 thr = 8 waves (2M x 4N), per-wave 128x64, BK=64, dbuf LDS 128KB.
// T2: col8 ^= (row&7) swizzle, write-side applied on global SOURCE address
// (global_load_lds dest must stay linear), read-side same involution.
// T3/T4: 4 phases/K-tile; stage t+1 A-halves ph1/ph2 (idle buffer),
// t+2 B-halves ph3/ph4 (current buffer, regions dead after ph2);
// single vmcnt(4) per block => tile t+1 landed, t+2's 4 loads in flight.
// T5: setprio(1) around each 16-MFMA cluster.
// MODE: 0 = bf16 out (C0 + z*sC, ldC); 1 = f32 + bias b0p; 2 = QKV route.
template <int MODE>
__global__ __launch_bounds__(512, 2) void k_gemm8(
    const short* __restrict__ A, const short* __restrict__ B,
    const float* __restrict__ b0p, const float* __restrict__ b1p,
    const float* __restrict__ b2p,
    void* __restrict__ C0, void* __restrict__ C1, void* __restrict__ C2,
    int K, long sA, long sB, long sC, int ldC) {
  __shared__ __align__(16) short lsA[2][16384];
  __shared__ __align__(16) short lsB[2][16384];
  const int tid = threadIdx.x;
  const int lane = tid & 63, wid = tid >> 6;
  const int wr = wid >> 2, wc = wid & 3;
  const int fr = lane & 15, fq = lane >> 4, fr7 = lane & 7;
  const int bm = blockIdx.x << 8, bn = blockIdx.y << 8;
  const short* Ab = A + (long)blockIdx.z * sA + (long)bm * K;
  const short* Bb = B + (long)blockIdx.z * sB + (long)bn * K;
  const int nt = K >> 6;

  // staging geometry: chunk0 = rows 0..63 of a 128-row half, chunk1 = +64 rows
  const long g0 = (long)(tid >> 3) * K + (long)(((tid & 7) ^ ((tid >> 3) & 7)) << 3);
  const long gstep = (long)K << 6;

  auto stage = [&](const short* mb, short* lb, int half, int kto) {
    const short* s0 = mb + (long)(half << 7) * K + kto + g0;
    short* l0 = lb + (half << 13) + (tid << 3);
    __builtin_amdgcn_global_load_lds(
        (const __attribute__((address_space(1))) void*)s0,
        (__attribute__((address_space(3))) void*)l0, 16, 0, 0);
    __builtin_amdgcn_global_load_lds(
        (const __attribute__((address_space(1))) void*)(s0 + gstep),
        (__attribute__((address_space(3))) void*)(l0 + 4096), 16, 0, 0);
  };

  const int aoffBase = ((wr << 7) + fr) << 6;   // (wr*128+fr)*64 elems
  const int boffBase = ((wc << 6) + fr) << 6;   // (wc*64+fr)*64
  const int ck0 = ((fq) ^ fr7) << 3;            // ks0 swizzled col (elems)
  const int ck1 = ((4 + fq) ^ fr7) << 3;        // ks1

  f32x4 acc[8][4] = {};

  // ---- prologue: tile0 fully, tile1 B-halves; leave 4 loads in flight ----
  stage(Ab, &lsA[0][0], 0, 0);
  stage(Ab, &lsA[0][0], 1, 0);
  stage(Bb, &lsB[0][0], 0, 0);
  stage(Bb, &lsB[0][0], 1, 0);
  if (nt > 1) {
    stage(Bb, &lsB[1][0], 0, 64);
    stage(Bb, &lsB[1][0], 1, 64);
    asm volatile("s_waitcnt vmcnt(4)" ::: "memory");
  } else {
    asm volatile("s_waitcnt vmcnt(0)" ::: "memory");
  }
  __builtin_amdgcn_s_barrier();

  int cur = 0;
  for (int t = 0; t < nt; ++t, cur ^= 1) {
    const int kt = t << 6;
    const bool h1 = (t + 1) < nt, h2 = (t + 2) < nt;
    const short* cA = &lsA[cur][0];
    const short* cB = &lsB[cur][0];
    short* nA = &lsA[cur ^ 1][0];
    short* wB = &lsB[cur][0];     // tile t+2 target (same parity)

    bf16x8 a[4], bb0[4], bb1[4];

    // ---- phase 1: (mh0, ks0) + stage t+1 A-half0 ----
    if (h1) stage(Ab, nA, 0, kt + 64);
#pragma unroll
    for (int j = 0; j < 4; ++j) a[j] = ld8(cA + aoffBase + j * 1024 + ck0);
#pragma unroll
    for (int n = 0; n < 4; ++n) bb0[n] = ld8(cB + boffBase + n * 1024 + ck0);
    __builtin_amdgcn_s_barrier();
    __builtin_amdgcn_s_setprio(1);
#pragma unroll
    for (int j = 0; j < 4; ++j)
#pragma unroll
      for (int n = 0; n < 4; ++n)
        acc[j][n] = __builtin_amdgcn_mfma_f32_16x16x32_bf16(a[j], bb0[n], acc[j][n], 0, 0, 0);
    __builtin_amdgcn_s_setprio(0);
    __builtin_amdgcn_s_barrier();

    // ---- phase 2: (mh0, ks1) + stage t+1 A-half1 ----
    if (h1) stage(Ab, nA, 1, kt + 64);
#pragma unroll
    for (int j = 0; j < 4; ++j) a[j] = ld8(cA + aoffBase + j * 1024 + ck1);
#pragma unroll
    for (int n = 0; n < 4; ++n) bb1[n] = ld8(cB + boffBase + n * 1024 + ck1);
    __builtin_amdgcn_s_barrier();
    __builtin_amdgcn_s_setprio(1);
#pragma unroll
    for (int j = 0; j < 4; ++j)
#pragma unroll
      for (int n = 0; n < 4; ++n)
        acc[j][n] = __builtin_amdgcn_mfma_f32_16x16x32_bf16(a[j], bb1[n], acc[j][n], 0, 0, 0);
    __builtin_amdgcn_s_setprio(0);
    __builtin_amdgcn_s_barrier();

    // ---- phase 3: (mh1, ks0) + stage t+2 B-half0 (region dead since ph2) ----
    if (h2) stage(Bb, wB, 0, kt + 128);
#pragma unroll
    for (int j = 0; j < 4; ++j) a[j] = ld8(cA + aoffBase + 4096 + j * 1024 + ck0);
    __builtin_amdgcn_s_barrier();
    __builtin_amdgcn_s_setprio(1);
#pragma unroll
    for (int j = 0; j < 4; ++j)
#pragma unroll
      for (int n = 0; n < 4; ++n)
        acc[4 + j][n] = __builtin_amdgcn_mfma_f32_16x16x32_bf16(a[j], bb0[n], acc[4 + j][n], 0, 0, 0);
    __builtin_amdgcn_s_setprio(0);
    __builtin_amdgcn_s_barrier();

    // ---- phase 4: (mh1, ks1) + stage t+2 B-half1; counted vmcnt ----
    if (h2) stage(Bb, wB, 1, kt + 128);
#pragma unroll
    for (int j = 0; j < 4; ++j) a[j] = ld8(cA + aoffBase + 4096 + j * 1024 + ck1);
    __builtin_amdgcn_s_barrier();
    __builtin_amdgcn_s_setprio(1);
#pragma unroll
    for (int j = 0; j < 4; ++j)
#pragma unroll
      for (int n = 0; n < 4; ++n)
        acc[4 + j][n] = __builtin_amdgcn_mfma_f32_16x16x32_bf16(a[j], bb1[n], acc[4 + j][n], 0, 0, 0);
    __builtin_amdgcn_s_setprio(0);
    if (h2)      asm volatile("s_waitcnt vmcnt(4)" ::: "memory");
    else if (h1) asm volatile("s_waitcnt vmcnt(0)" ::: "memory");
    __builtin_amdgcn_s_barrier();
  }

  // ---- epilogue ----
#pragma unroll
  for (int M_ = 0; M_ < 8; ++M_) {
    const int row0 = bm + (wr << 7) + M_ * 16 + (fq << 2);
#pragma unroll
    for (int n = 0; n < 4; ++n) {
      const int coll = (wc << 6) + n * 16 + fr;
      if constexpr (MODE == 0) {
        short* O = (short*)C0 + (long)blockIdx.z * sC;
        const int col = bn + coll;
#pragma unroll
        for (int i = 0; i < 4; ++i)
          O[(long)(row0 + i) * ldC + col] = f2bf(acc[M_][n][i]);
      } else if constexpr (MODE == 1) {
        float* O = (float*)C0;
        const int col = bn + coll;
        const float bv = b0p[col];
#pragma unroll
        for (int i = 0; i < 4; ++i)
          O[(long)(row0 + i) * ldC + col] = acc[M_][n][i] + bv;
      } else {  // QKV route: sel by global col block
        const int sel = bn >> 10;
        const int cl = (bn & 1023) + coll;
        const float bv = (sel == 0 ? b0p : sel == 1 ? b1p : b2p)[cl];
#pragma unroll
        for (int i = 0; i < 4; ++i) {
          const float v = acc[M_][n][i] + bv;
          const int r = row0 + i;
          if (sel == 0) {
            ((short*)C0)[(long)r * 1024 + cl] = f2bf(v);
          } else if (sel == 1) {
            ((short*)C1)[(long)r * 1024 + cl] = f2bf(v);
          } else {  // V, stored transposed: vT[b][e][s]
            const int b = r >> 11, s = r & 2047;
            ((short*)C2)[((long)b << 21) + ((long)cl << 11) + s] = f2bf(v);
          }
        }
      }
    }
  }
}

// ---------- in-place row softmax on bf16 scores, rows of 2048, scale 1/32 ----------
__global__ __launch_bounds__(256) void k_softmax(short* __restrict__ S) {
  const long base = (long)blockIdx.x * 2048;
  const int t = threadIdx.x, lane = t & 63, wid = t >> 6;
  short8v raw = *reinterpret_cast<const short8v*>(S + base + t * 8);
  float x[8];
#pragma unroll
  for (int j = 0; j < 8; ++j) x[j] = bf2f(raw[j]) * 0.03125f;
  float m = x[0];
#pragma unroll
  for (int j = 1; j < 8; ++j) m = fmaxf(m, x[j]);
#pragma unroll
  for (int off = 32; off; off >>= 1) m = fmaxf(m, __shfl_xor(m, off));
  __shared__ float rmax[4], rsum[4];
  if (lane == 0) rmax[wid] = m;
  __syncthreads();
  m = fmaxf(fmaxf(rmax[0], rmax[1]), fmaxf(rmax[2], rmax[3]));
  float e[8], s = 0.f;
#pragma unroll
  for (int j = 0; j < 8; ++j) { e[j] = __expf(x[j] - m); s += e[j]; }
#pragma unroll
  for (int off = 32; off; off >>= 1) s += __shfl_xor(s, off);
  if (lane == 0) rsum[wid] = s;
  __syncthreads();
  s = rsum[0] + rsum[1] + rsum[2] + rsum[3];
  float inv = 1.0f / s;
  short8v o;
#pragma unroll
  for (int j = 0; j < 8; ++j) o[j] = f2bf(e[j] * inv);
  *reinterpret_cast<short8v*>(S + base + t * 8) = o;
}

// ---------- launcher ----------
extern "C" void kernel_launch(void* const* d_in, const int* in_sizes, int n_in,
                              void* d_out, int out_size, void* d_ws, size_t ws_size,
                              hipStream_t stream) {
  const float* x  = (const float*)d_in[0];
  const float* Wq = (const float*)d_in[1];
  const float* bq = (const float*)d_in[2];
  const float* Wk = (const float*)d_in[3];
  const float* bk = (const float*)d_in[4];
  const float* Wv = (const float*)d_in[5];
  const float* bv = (const float*)d_in[6];
  const float* Wo = (const float*)d_in[7];
  const float* bo = (const float*)d_in[8];

  // ws layout: every region fully overwritten before read each call.
  char* ws = (char*)d_ws;
  short* xb    = (short*)ws; ws += 8192L * 1024 * 2;     // x bf16
  short* wqkvb = (short*)ws; ws += 3072L * 1024 * 2;     // [Wq;Wk;Wv] bf16
  short* wob   = (short*)ws; ws += 1024L * 1024 * 2;
  short* qb    = (short*)ws; ws += 8192L * 1024 * 2;     // Q
  short* kb    = (short*)ws; ws += 8192L * 1024 * 2;     // K
  short* vT    = (short*)ws; ws += 8192L * 1024 * 2;     // V^T per batch [b][e][s]
  short* Sc    = (short*)ws; ws += 4L * 2048 * 2048 * 2; // scores -> probs
  short* ao    = (short*)ws; ws += 8192L * 1024 * 2;     // attn output

  dim3 b256(256), b512(512);
  k_cvt<<<8192, b256, 0, stream>>>(x,  xb, 2097152);
  k_cvt<<<1024, b256, 0, stream>>>(Wq, wqkvb,               262144);
  k_cvt<<<1024, b256, 0, stream>>>(Wk, wqkvb + 1024L * 1024, 262144);
  k_cvt<<<1024, b256, 0, stream>>>(Wv, wqkvb + 2048L * 1024, 262144);
  k_cvt<<<1024, b256, 0, stream>>>(Wo, wob, 262144);

  // fused QKV projection: [8192,3072] = x * [Wq;Wk;Wv]^T, routed epilogue
  k_gemm8<2><<<dim3(32, 12, 1), b512, 0, stream>>>(
      xb, wqkvb, bq, bk, bv, qb, kb, vT, 1024, 0, 0, 0, 0);
  // scores[b] = Q[b] * K[b]^T   (M=N=2048, K=1024)
  k_gemm8<0><<<dim3(8, 8, 4), b512, 0, stream>>>(
      qb, kb, nullptr, nullptr, nullptr, Sc, nullptr, nullptr,
      1024, 2048L * 1024, 2048L * 1024, 2048L * 2048, 2048);
  // softmax rows (scale 1/32 folded in), in place
  k_softmax<<<8192, b256, 0, stream>>>(Sc);
  // attn_out[b] = P[b] * V[b]   (A=P [2048,2048], B=vT[b] [1024,2048])
  k_gemm8<0><<<dim3(8, 4, 4), b512, 0, stream>>>(
      Sc, vT, nullptr, nullptr, nullptr, ao, nullptr, nullptr,
      2048, 2048L * 2048, 1024L * 2048, 2048L * 1024, 1024);
  // y = ao * Wo^T + bo -> fp32 d_out
  k_gemm8<1><<<dim3(32, 4, 1), b512, 0, stream>>>(
      ao, wob, bo, nullptr, nullptr, (float*)d_out, nullptr, nullptr,
      1024, 0, 0, 0, 1024);
}

// Round 4
// 262.581 us; speedup vs baseline: 1.1721x; 1.1721x over previous
//
#include <hip/hip_runtime.h>

typedef short  short4v __attribute__((ext_vector_type(4)));
typedef short  short8v __attribute__((ext_vector_type(8)));
typedef __bf16 bf16x8  __attribute__((ext_vector_type(8)));
typedef float  f32x4   __attribute__((ext_vector_type(4)));
typedef float  float4v __attribute__((ext_vector_type(4)));

__device__ __forceinline__ short f2bf(float f) {
  unsigned u = __builtin_bit_cast(unsigned, f);
  u += 0x7fffu + ((u >> 16) & 1u);   // RNE
  return (short)(u >> 16);
}
__device__ __forceinline__ float bf2f(short h) {
  unsigned u = ((unsigned)(unsigned short)h) << 16;
  return __builtin_bit_cast(float, u);
}
__device__ __forceinline__ bf16x8 ld8(const short* p) {
  return __builtin_bit_cast(bf16x8, *reinterpret_cast<const short8v*>(p));
}

// ---------- fp32 -> bf16 convert ----------
__global__ __launch_bounds__(256) void k_cvt(const float* __restrict__ in,
                                             short* __restrict__ out, int n4) {
  int i = blockIdx.x * 256 + threadIdx.x;
  if (i >= n4) return;
  float4v v = *reinterpret_cast<const float4v*>(in + (long)i * 4);
  short4v o;
  o[0] = f2bf(v[0]); o[1] = f2bf(v[1]); o[2] = f2bf(v[2]); o[3] = f2bf(v[3]);
  *reinterpret_cast<short4v*>(out + (long)i * 4) = o;
}

// fused weight converts: blockIdx.y selects one of 4 [1024x1024] matrices
__global__ __launch_bounds__(256) void k_cvtw(const float* __restrict__ w0,
    const float* __restrict__ w1, const float* __restrict__ w2,
    const float* __restrict__ w3, short* __restrict__ o0, short* __restrict__ o1,
    short* __restrict__ o2, short* __restrict__ o3) {
  const float* in = blockIdx.y == 0 ? w0 : blockIdx.y == 1 ? w1 : blockIdx.y == 2 ? w2 : w3;
  short* out = blockIdx.y == 0 ? o0 : blockIdx.y == 1 ? o1 : blockIdx.y == 2 ? o2 : o3;
  int i = blockIdx.x * 256 + threadIdx.x;
  float4v v = *reinterpret_cast<const float4v*>(in + (long)i * 4);
  short4v o;
  o[0] = f2bf(v[0]); o[1] = f2bf(v[1]); o[2] = f2bf(v[2]); o[3] = f2bf(v[3]);
  *reinterpret_cast<short4v*>(out + (long)i * 4) = o;
}

// ---------- BMx256 hoisted-read pipelined GEMM: C = A[M,K]*B[N,K]^T ----------
// 512 thr = 8 waves. BM=256: waves 2Mx4N (per-wave 128x64); BM=128: 1Mx8N
// (per-wave 128x32). BK=64, double-buffered LDS (128KB / 96KB), T2 swizzle
// (pre-swizzled global source + same-involution read), counted vmcnt(4) once
// per K-tile (prologue 12-issued->wait4; steady 8/8; tail ->0), 2 barriers
// per K-tile (only the hazard-required ones: B-stage WAW guard + tile RAW),
// ds_reads source-hoisted >=1 phase before their MFMA use, setprio on MFMA.
// MODE: 0 = bf16 out; 1 = f32 + bias; 2 = QKV routed epilogue.
template <int BM, int MODE>
__global__ __launch_bounds__(512, 2) void k8(
    const short* __restrict__ A, const short* __restrict__ B,
    const float* __restrict__ b0p, const float* __restrict__ b1p,
    const float* __restrict__ b2p,
    void* __restrict__ C0, void* __restrict__ C1, void* __restrict__ C2,
    int K, long sA, long sB, long sC, int ldC) {
  constexpr int NF = (BM == 256) ? 4 : 2;      // B fragments per wave
  __shared__ __align__(16) short lsA[2][BM * 64];
  __shared__ __align__(16) short lsB[2][16384];
  const int tid = threadIdx.x;
  const int lane = tid & 63, wid = tid >> 6;
  const int wr = (BM == 256) ? (wid >> 2) : 0;
  const int wc = (BM == 256) ? (wid & 3) : wid;
  const int fr = lane & 15, fq = lane >> 4, fr7 = lane & 7;
  const int bm = blockIdx.x * BM, bn = blockIdx.y << 8;
  const short* Ab = A + (long)blockIdx.z * sA + (long)bm * K;
  const short* Bb = B + (long)blockIdx.z * sB + (long)bn * K;
  const int nt = K >> 6;

  const long g0 = (long)(tid >> 3) * K + (long)(((tid & 7) ^ ((tid >> 3) & 7)) << 3);
  const long gstep = (long)K << 6;

  auto stage = [&](const short* mb, short* lb, int half, int kto) {
    const short* s0 = mb + (long)(half << 7) * K + kto + g0;
    short* l0 = lb + (half << 13) + (tid << 3);
    __builtin_amdgcn_global_load_lds(
        (const __attribute__((address_space(1))) void*)s0,
        (__attribute__((address_space(3))) void*)l0, 16, 0, 0);
    __builtin_amdgcn_global_load_lds(
        (const __attribute__((address_space(1))) void*)(s0 + gstep),
        (__attribute__((address_space(3))) void*)(l0 + 4096), 16, 0, 0);
  };

  const int aoffBase = ((wr << 7) + fr) << 6;
  const int boffBase = (wc * (NF * 16) + fr) << 6;
  const int ck0 = (fq ^ fr7) << 3;
  const int ck1 = ((4 + fq) ^ fr7) << 3;

  f32x4 acc[8][NF] = {};

  // ---- prologue: tile0 (A+B) + tile1 B; wait(4) leaves tile1-B in flight ----
  if constexpr (BM == 256) { stage(Ab, &lsA[0][0], 0, 0); stage(Ab, &lsA[0][0], 1, 0); }
  else                     { stage(Ab, &lsA[0][0], 0, 0); }
  stage(Bb, &lsB[0][0], 0, 0);
  stage(Bb, &lsB[0][0], 1, 0);
  if (nt > 1) {
    stage(Bb, &lsB[1][0], 0, 64);
    stage(Bb, &lsB[1][0], 1, 64);
    asm volatile("s_waitcnt vmcnt(4)" ::: "memory");
  } else {
    asm volatile("s_waitcnt vmcnt(0)" ::: "memory");
  }
  __builtin_amdgcn_s_barrier();

  int cur = 0;
  for (int t = 0; t < nt; ++t, cur ^= 1) {
    const int kt = t << 6;
    const bool h1 = (t + 1) < nt, h2 = (t + 2) < nt;
    const short* cA = &lsA[cur][0];
    const short* cB = &lsB[cur][0];
    short* nA = &lsA[cur ^ 1][0];
    short* wB = &lsB[cur][0];   // tile t+2 target (same parity)

    if constexpr (BM == 256) {
      bf16x8 a0[4], a1_[4], a2_[4], a3_[4], bb0[4], bb1[4];
      // ---- super-phase 1: stage next-A; read a0,bb0 then bb1,a1,a2; 32 MFMA ----
      if (h1) { stage(Ab, nA, 0, kt + 64); stage(Ab, nA, 1, kt + 64); }
#pragma unroll
      for (int j = 0; j < 4; ++j) a0[j]  = ld8(cA + aoffBase + j * 1024 + ck0);
#pragma unroll
      for (int n = 0; n < 4; ++n) bb0[n] = ld8(cB + boffBase + n * 1024 + ck0);
#pragma unroll
      for (int n = 0; n < 4; ++n) bb1[n] = ld8(cB + boffBase + n * 1024 + ck1);
#pragma unroll
      for (int j = 0; j < 4; ++j) a1_[j] = ld8(cA + aoffBase + j * 1024 + ck1);
#pragma unroll
      for (int j = 0; j < 4; ++j) a2_[j] = ld8(cA + aoffBase + 4096 + j * 1024 + ck0);
      __builtin_amdgcn_s_setprio(1);
#pragma unroll
      for (int m = 0; m < 4; ++m)
#pragma unroll
        for (int n = 0; n < 4; ++n)
          acc[m][n] = __builtin_amdgcn_mfma_f32_16x16x32_bf16(a0[m], bb0[n], acc[m][n], 0, 0, 0);
#pragma unroll
      for (int m = 0; m < 4; ++m)
#pragma unroll
        for (int n = 0; n < 4; ++n)
          acc[m][n] = __builtin_amdgcn_mfma_f32_16x16x32_bf16(a1_[m], bb1[n], acc[m][n], 0, 0, 0);
      __builtin_amdgcn_s_setprio(0);
      __builtin_amdgcn_s_barrier();   // all waves' B reads complete -> B-stage safe
      // ---- super-phase 2: stage next-next-B; read a3; 32 MFMA ----
      if (h2) { stage(Bb, wB, 0, kt + 128); stage(Bb, wB, 1, kt + 128); }
#pragma unroll
      for (int j = 0; j < 4; ++j) a3_[j] = ld8(cA + aoffBase + 4096 + j * 1024 + ck1);
      __builtin_amdgcn_s_setprio(1);
#pragma unroll
      for (int m = 0; m < 4; ++m)
#pragma unroll
        for (int n = 0; n < 4; ++n)
          acc[4 + m][n] = __builtin_amdgcn_mfma_f32_16x16x32_bf16(a2_[m], bb0[n], acc[4 + m][n], 0, 0, 0);
#pragma unroll
      for (int m = 0; m < 4; ++m)
#pragma unroll
        for (int n = 0; n < 4; ++n)
          acc[4 + m][n] = __builtin_amdgcn_mfma_f32_16x16x32_bf16(a3_[m], bb1[n], acc[4 + m][n], 0, 0, 0);
      __builtin_amdgcn_s_setprio(0);
      if (h2)      asm volatile("s_waitcnt vmcnt(4)" ::: "memory");
      else if (h1) asm volatile("s_waitcnt vmcnt(0)" ::: "memory");
      __builtin_amdgcn_s_barrier();   // tile boundary
    } else {
      bf16x8 a0[4], a1_[4], a2_[4], a3_[4], bb0[2], bb1[2];
      // ---- super-phase 1 (ks0): stage next-A; read bb0,a0,a2,bb1; 16 MFMA ----
      if (h1) stage(Ab, nA, 0, kt + 64);
#pragma unroll
      for (int j = 0; j < 4; ++j) a0[j]  = ld8(cA + aoffBase + j * 1024 + ck0);
#pragma unroll
      for (int n = 0; n < 2; ++n) bb0[n] = ld8(cB + boffBase + n * 1024 + ck0);
#pragma unroll
      for (int n = 0; n < 2; ++n) bb1[n] = ld8(cB + boffBase + n * 1024 + ck1);
#pragma unroll
      for (int j = 0; j < 4; ++j) a2_[j] = ld8(cA + aoffBase + 4096 + j * 1024 + ck0);
      __builtin_amdgcn_s_setprio(1);
#pragma unroll
      for (int m = 0; m < 4; ++m)
#pragma unroll
        for (int n = 0; n < 2; ++n)
          acc[m][n] = __builtin_amdgcn_mfma_f32_16x16x32_bf16(a0[m], bb0[n], acc[m][n], 0, 0, 0);
#pragma unroll
      for (int m = 0; m < 4; ++m)
#pragma unroll
        for (int n = 0; n < 2; ++n)
          acc[4 + m][n] = __builtin_amdgcn_mfma_f32_16x16x32_bf16(a2_[m], bb0[n], acc[4 + m][n], 0, 0, 0);
      __builtin_amdgcn_s_setprio(0);
      asm volatile("s_waitcnt lgkmcnt(0)" ::: "memory");  // bb1 fully landed
      __builtin_amdgcn_sched_barrier(0);
      __builtin_amdgcn_s_barrier();   // -> B-stage safe
      // ---- super-phase 2 (ks1): stage next-next-B; read a1,a3; 16 MFMA ----
      if (h2) { stage(Bb, wB, 0, kt + 128); stage(Bb, wB, 1, kt + 128); }
#pragma unroll
      for (int j = 0; j < 4; ++j) a1_[j] = ld8(cA + aoffBase + j * 1024 + ck1);
#pragma unroll
      for (int j = 0; j < 4; ++j) a3_[j] = ld8(cA + aoffBase + 4096 + j * 1024 + ck1);
      __builtin_amdgcn_s_setprio(1);
#pragma unroll
      for (int m = 0; m < 4; ++m)
#pragma unroll
        for (int n = 0; n < 2; ++n)
          acc[m][n] = __builtin_amdgcn_mfma_f32_16x16x32_bf16(a1_[m], bb1[n], acc[m][n], 0, 0, 0);
#pragma unroll
      for (int m = 0; m < 4; ++m)
#pragma unroll
        for (int n = 0; n < 2; ++n)
          acc[4 + m][n] = __builtin_amdgcn_mfma_f32_16x16x32_bf16(a3_[m], bb1[n], acc[4 + m][n], 0, 0, 0);
      __builtin_amdgcn_s_setprio(0);
      if (h2)      asm volatile("s_waitcnt vmcnt(4)" ::: "memory");
      else if (h1) asm volatile("s_waitcnt vmcnt(0)" ::: "memory");
      __builtin_amdgcn_s_barrier();   // tile boundary
    }
  }

  __builtin_amdgcn_sched_barrier(0);  // keep epilogue vmem out of the loop ledger

  // ---- epilogue ----
#pragma unroll
  for (int M_ = 0; M_ < 8; ++M_) {
    const int row0 = bm + (wr << 7) + M_ * 16 + (fq << 2);
#pragma unroll
    for (int n = 0; n < NF; ++n) {
      const int coll = wc * (NF * 16) + n * 16 + fr;
      if constexpr (MODE == 0) {
        short* O = (short*)C0 + (long)blockIdx.z * sC;
        const int col = bn + coll;
#pragma unroll
        for (int i = 0; i < 4; ++i)
          O[(long)(row0 + i) * ldC + col] = f2bf(acc[M_][n][i]);
      } else if constexpr (MODE == 1) {
        float* O = (float*)C0;
        const int col = bn + coll;
        const float bv = b0p[col];
#pragma unroll
        for (int i = 0; i < 4; ++i)
          O[(long)(row0 + i) * ldC + col] = acc[M_][n][i] + bv;
      } else {  // QKV routed
        const int sel = bn >> 10;
        const int cl = (bn & 1023) + coll;
        const float bv = (sel == 0 ? b0p : sel == 1 ? b1p : b2p)[cl];
#pragma unroll
        for (int i = 0; i < 4; ++i) {
          const float v = acc[M_][n][i] + bv;
          const int r = row0 + i;
          if (sel == 0) {
            ((short*)C0)[(long)r * 1024 + cl] = f2bf(v);
          } else if (sel == 1) {
            ((short*)C1)[(long)r * 1024 + cl] = f2bf(v);
          } else {  // V stored transposed: vT[b][e][s]
            const int b = r >> 11, s = r & 2047;
            ((short*)C2)[((long)b << 21) + ((long)cl << 11) + s] = f2bf(v);
          }
        }
      }
    }
  }
}

// ---------- in-place row softmax on bf16 scores, rows of 2048, scale 1/32 ----------
__global__ __launch_bounds__(256) void k_softmax(short* __restrict__ S) {
  const long base = (long)blockIdx.x * 2048;
  const int t = threadIdx.x, lane = t & 63, wid = t >> 6;
  short8v raw = *reinterpret_cast<const short8v*>(S + base + t * 8);
  float x[8];
#pragma unroll
  for (int j = 0; j < 8; ++j) x[j] = bf2f(raw[j]) * 0.03125f;
  float m = x[0];
#pragma unroll
  for (int j = 1; j < 8; ++j) m = fmaxf(m, x[j]);
#pragma unroll
  for (int off = 32; off; off >>= 1) m = fmaxf(m, __shfl_xor(m, off));
  __shared__ float rmax[4], rsum[4];
  if (lane == 0) rmax[wid] = m;
  __syncthreads();
  m = fmaxf(fmaxf(rmax[0], rmax[1]), fmaxf(rmax[2], rmax[3]));
  float e[8], s = 0.f;
#pragma unroll
  for (int j = 0; j < 8; ++j) { e[j] = __expf(x[j] - m); s += e[j]; }
#pragma unroll
  for (int off = 32; off; off >>= 1) s += __shfl_xor(s, off);
  if (lane == 0) rsum[wid] = s;
  __syncthreads();
  s = rsum[0] + rsum[1] + rsum[2] + rsum[3];
  float inv = 1.0f / s;
  short8v o;
#pragma unroll
  for (int j = 0; j < 8; ++j) o[j] = f2bf(e[j] * inv);
  *reinterpret_cast<short8v*>(S + base + t * 8) = o;
}

// ---------- launcher ----------
extern "C" void kernel_launch(void* const* d_in, const int* in_sizes, int n_in,
                              void* d_out, int out_size, void* d_ws, size_t ws_size,
                              hipStream_t stream) {
  const float* x  = (const float*)d_in[0];
  const float* Wq = (const float*)d_in[1];
  const float* bq = (const float*)d_in[2];
  const float* Wk = (const float*)d_in[3];
  const float* bk = (const float*)d_in[4];
  const float* Wv = (const float*)d_in[5];
  const float* bv = (const float*)d_in[6];
  const float* Wo = (const float*)d_in[7];
  const float* bo = (const float*)d_in[8];

  char* ws = (char*)d_ws;
  short* xb    = (short*)ws; ws += 8192L * 1024 * 2;
  short* wqkvb = (short*)ws; ws += 3072L * 1024 * 2;     // [Wq;Wk;Wv]
  short* wob   = (short*)ws; ws += 1024L * 1024 * 2;
  short* qb    = (short*)ws; ws += 8192L * 1024 * 2;
  short* kb    = (short*)ws; ws += 8192L * 1024 * 2;
  short* vT    = (short*)ws; ws += 8192L * 1024 * 2;     // [b][e][s]
  short* Sc    = (short*)ws; ws += 4L * 2048 * 2048 * 2;
  short* ao    = (short*)ws; ws += 8192L * 1024 * 2;

  dim3 b256(256), b512(512);
  k_cvt<<<8192, b256, 0, stream>>>(x, xb, 2097152);
  k_cvtw<<<dim3(1024, 4, 1), b256, 0, stream>>>(
      Wq, Wk, Wv, Wo, wqkvb, wqkvb + 1024L * 1024, wqkvb + 2048L * 1024, wob);

  // QKV: [8192,3072] = x * [Wq;Wk;Wv]^T, 128x256 tiles -> 768 blocks = 3.0 rounds
  k8<128, 2><<<dim3(64, 12, 1), b512, 0, stream>>>(
      xb, wqkvb, bq, bk, bv, qb, kb, vT, 1024, 0, 0, 0, 0);
  // scores[b] = Q[b]*K[b]^T, 256x256 tiles -> 256 blocks = 1.0 round
  k8<256, 0><<<dim3(8, 8, 4), b512, 0, stream>>>(
      qb, kb, nullptr, nullptr, nullptr, Sc, nullptr, nullptr,
      1024, 2048L * 1024, 2048L * 1024, 2048L * 2048, 2048);
  k_softmax<<<8192, b256, 0, stream>>>(Sc);
  // PV: [2048,1024] per batch, 128x256 tiles -> 256 blocks
  k8<128, 0><<<dim3(16, 4, 4), b512, 0, stream>>>(
      Sc, vT, nullptr, nullptr, nullptr, ao, nullptr, nullptr,
      2048, 2048L * 2048, 1024L * 2048, 2048L * 1024, 1024);
  // out = ao * Wo^T + bo, 128x256 tiles -> 256 blocks
  k8<128, 1><<<dim3(64, 4, 1), b512, 0, stream>>>(
      ao, wob, bo, nullptr, nullptr, (float*)d_out, nullptr, nullptr,
      1024, 0, 0, 0, 1024);
}

// Round 5
// 232.520 us; speedup vs baseline: 1.3237x; 1.1293x over previous
//
#include <hip/hip_runtime.h>

typedef short  short4v __attribute__((ext_vector_type(4)));
typedef short  short8v __attribute__((ext_vector_type(8)));
typedef __bf16 bf16x8  __attribute__((ext_vector_type(8)));
typedef float  f32x4   __attribute__((ext_vector_type(4)));
typedef float  float4v __attribute__((ext_vector_type(4)));

__device__ __forceinline__ short f2bf(float f) {
  unsigned u = __builtin_bit_cast(unsigned, f);
  u += 0x7fffu + ((u >> 16) & 1u);   // RNE
  return (short)(u >> 16);
}
__device__ __forceinline__ float bf2f(short h) {
  unsigned u = ((unsigned)(unsigned short)h) << 16;
  return __builtin_bit_cast(float, u);
}
__device__ __forceinline__ bf16x8 ld8(const short* p) {
  return __builtin_bit_cast(bf16x8, *reinterpret_cast<const short8v*>(p));
}

// ---------- fp32 -> bf16 convert ----------
__global__ __launch_bounds__(256) void k_cvt(const float* __restrict__ in,
                                             short* __restrict__ out, int n4) {
  int i = blockIdx.x * 256 + threadIdx.x;
  if (i >= n4) return;
  float4v v = *reinterpret_cast<const float4v*>(in + (long)i * 4);
  short4v o;
  o[0] = f2bf(v[0]); o[1] = f2bf(v[1]); o[2] = f2bf(v[2]); o[3] = f2bf(v[3]);
  *reinterpret_cast<short4v*>(out + (long)i * 4) = o;
}

// 3 weight matrices fp32->bf16 (Wq, Wk, Wo)
__global__ __launch_bounds__(256) void k_cvtw(const float* __restrict__ w0,
    const float* __restrict__ w1, const float* __restrict__ w2,
    short* __restrict__ o0, short* __restrict__ o1, short* __restrict__ o2) {
  const float* in = blockIdx.y == 0 ? w0 : blockIdx.y == 1 ? w1 : w2;
  short* out = blockIdx.y == 0 ? o0 : blockIdx.y == 1 ? o1 : o2;
  int i = blockIdx.x * 256 + threadIdx.x;
  float4v v = *reinterpret_cast<const float4v*>(in + (long)i * 4);
  short4v o;
  o[0] = f2bf(v[0]); o[1] = f2bf(v[1]); o[2] = f2bf(v[2]); o[3] = f2bf(v[3]);
  *reinterpret_cast<short4v*>(out + (long)i * 4) = o;
}

// transposed convert: Wv f32 [e,d] -> wvT bf16 [d,e]  (1024x1024)
__global__ __launch_bounds__(256) void k_cvtT(const float* __restrict__ in,
                                              short* __restrict__ out) {
  __shared__ float tile[16][17];
  const int lx = threadIdx.x & 15, ly = threadIdx.x >> 4;
  const int bx = blockIdx.x << 4, by = blockIdx.y << 4;
  tile[ly][lx] = in[(long)(by + ly) * 1024 + bx + lx];
  __syncthreads();
  out[(long)(bx + ly) * 1024 + by + lx] = f2bf(tile[lx][ly]);
}

// bv' = Wo (f32 [o,e]) * bv (f32 [e]) -> f32 [o];  4 rows/block (one per wave)
__global__ __launch_bounds__(256) void k_matvec(const float* __restrict__ W,
    const float* __restrict__ v, float* __restrict__ o) {
  const int row = blockIdx.x * 4 + (threadIdx.x >> 6), lane = threadIdx.x & 63;
  float s = 0.f;
#pragma unroll
  for (int j = 0; j < 16; ++j)
    s += W[(long)row * 1024 + j * 64 + lane] * v[j * 64 + lane];
#pragma unroll
  for (int off = 32; off; off >>= 1) s += __shfl_xor(s, off);
  if (lane == 0) o[row] = s;
}

// ---------- m97-core GEMM (R1-measured 634 TF): C = A[M,K]*B[N,K]^T ----------
// 128x128 tile, 256 thr = 4 waves (2x2), 4x4 16x16x32 frags/wave, BK=64,
// single-buffer 32KB LDS -> ~3 blocks/CU implicit overlap (m114).
// MODE 0: bf16 out (C0 + z*sC, ldC), no bias.
// MODE 1: f32 out + bias b0p (C0 + z*sC, ldC).
// MODE 2: QKV routed epilogue (Q->C0, K->C1, V'->C2 transposed [b][e][s]).
template <int MODE>
__global__ __launch_bounds__(256, 3) void k_gemm(
    const short* __restrict__ A, const short* __restrict__ B,
    const float* __restrict__ b0p, const float* __restrict__ b1p,
    const float* __restrict__ b2p,
    void* __restrict__ C0, void* __restrict__ C1, void* __restrict__ C2,
    int K, long sA, long sB, long sC, int ldC) {
  __shared__ __align__(16) short lsA[128 * 64];
  __shared__ __align__(16) short lsB[128 * 64];
  const int tid = threadIdx.x;
  const int lane = tid & 63;
  const int wid = tid >> 6;
  const int wr = wid >> 1, wc = wid & 1;
  const int fr = lane & 15, fq = lane >> 4;
  const int bm = blockIdx.x * 128, bn = blockIdx.y * 128;
  const short* Ab = A + (long)blockIdx.z * sA;
  const short* Bb = B + (long)blockIdx.z * sB;

  f32x4 acc[4][4] = {};

  for (int kt = 0; kt < K; kt += 64) {
    __syncthreads();
#pragma unroll
    for (int c = 0; c < 4; ++c) {
      int idx = c * 256 + tid;
      int row = idx >> 3;
      int colh = (idx & 7) << 3;
      const short* ga = Ab + (long)(bm + row) * K + kt + colh;
      const short* gb = Bb + (long)(bn + row) * K + kt + colh;
      __builtin_amdgcn_global_load_lds(
          (const __attribute__((address_space(1))) void*)ga,
          (__attribute__((address_space(3))) void*)&lsA[(long)idx * 8], 16, 0, 0);
      __builtin_amdgcn_global_load_lds(
          (const __attribute__((address_space(1))) void*)gb,
          (__attribute__((address_space(3))) void*)&lsB[(long)idx * 8], 16, 0, 0);
    }
    __syncthreads();
#pragma unroll
    for (int ks = 0; ks < 64; ks += 32) {
      bf16x8 a[4], b[4];
#pragma unroll
      for (int m = 0; m < 4; ++m)
        a[m] = ld8(&lsA[(wr * 64 + m * 16 + fr) * 64 + ks + fq * 8]);
#pragma unroll
      for (int n = 0; n < 4; ++n)
        b[n] = ld8(&lsB[(wc * 64 + n * 16 + fr) * 64 + ks + fq * 8]);
#pragma unroll
      for (int m = 0; m < 4; ++m)
#pragma unroll
        for (int n = 0; n < 4; ++n)
          acc[m][n] = __builtin_amdgcn_mfma_f32_16x16x32_bf16(a[m], b[n], acc[m][n], 0, 0, 0);
    }
  }

#pragma unroll
  for (int n = 0; n < 4; ++n) {
    const int coll = wc * 64 + n * 16 + fr;
#pragma unroll
    for (int m = 0; m < 4; ++m) {
      const int row0 = bm + wr * 64 + m * 16 + fq * 4;
#pragma unroll
      for (int i = 0; i < 4; ++i) {
        const float vacc = acc[m][n][i];
        if constexpr (MODE == 0) {
          short* O = (short*)C0 + (long)blockIdx.z * sC;
          O[(long)(row0 + i) * ldC + bn + coll] = f2bf(vacc);
        } else if constexpr (MODE == 1) {
          float* O = (float*)C0 + (long)blockIdx.z * sC;
          O[(long)(row0 + i) * ldC + bn + coll] = vacc + b0p[bn + coll];
        } else {  // QKV routed
          const int sel = (bn + coll) >> 10;
          const int cl = (bn + coll) & 1023;
          const float bv = (sel == 0 ? b0p : sel == 1 ? b1p : b2p)[cl];
          const float v = vacc + bv;
          const int r = row0 + i;
          if (sel == 0) {
            ((short*)C0)[(long)r * 1024 + cl] = f2bf(v);
          } else if (sel == 1) {
            ((short*)C1)[(long)r * 1024 + cl] = f2bf(v);
          } else {  // V' stored transposed: vT[b][e][s]
            const int b = r >> 11, s = r & 2047;
            ((short*)C2)[((long)b << 21) + ((long)cl << 11) + s] = f2bf(v);
          }
        }
      }
    }
  }
}

// ---------- in-place row softmax on bf16 scores, rows of 2048, scale 1/32 ----------
__global__ __launch_bounds__(256) void k_softmax(short* __restrict__ S) {
  const long base = (long)blockIdx.x * 2048;
  const int t = threadIdx.x, lane = t & 63, wid = t >> 6;
  short8v raw = *reinterpret_cast<const short8v*>(S + base + t * 8);
  float x[8];
#pragma unroll
  for (int j = 0; j < 8; ++j) x[j] = bf2f(raw[j]) * 0.03125f;
  float m = x[0];
#pragma unroll
  for (int j = 1; j < 8; ++j) m = fmaxf(m, x[j]);
#pragma unroll
  for (int off = 32; off; off >>= 1) m = fmaxf(m, __shfl_xor(m, off));
  __shared__ float rmax[4], rsum[4];
  if (lane == 0) rmax[wid] = m;
  __syncthreads();
  m = fmaxf(fmaxf(rmax[0], rmax[1]), fmaxf(rmax[2], rmax[3]));
  float e[8], s = 0.f;
#pragma unroll
  for (int j = 0; j < 8; ++j) { e[j] = __expf(x[j] - m); s += e[j]; }
#pragma unroll
  for (int off = 32; off; off >>= 1) s += __shfl_xor(s, off);
  if (lane == 0) rsum[wid] = s;
  __syncthreads();
  s = rsum[0] + rsum[1] + rsum[2] + rsum[3];
  float inv = 1.0f / s;
  short8v o;
#pragma unroll
  for (int j = 0; j < 8; ++j) o[j] = f2bf(e[j] * inv);
  *reinterpret_cast<short8v*>(S + base + t * 8) = o;
}

// ---------- launcher ----------
extern "C" void kernel_launch(void* const* d_in, const int* in_sizes, int n_in,
                              void* d_out, int out_size, void* d_ws, size_t ws_size,
                              hipStream_t stream) {
  const float* x  = (const float*)d_in[0];
  const float* Wq = (const float*)d_in[1];
  const float* bq = (const float*)d_in[2];
  const float* Wk = (const float*)d_in[3];
  const float* bk = (const float*)d_in[4];
  const float* Wv = (const float*)d_in[5];
  const float* bv = (const float*)d_in[6];
  const float* Wo = (const float*)d_in[7];
  const float* bo = (const float*)d_in[8];

  // ws layout: every region fully overwritten before read each call.
  char* ws = (char*)d_ws;
  short* xb    = (short*)ws; ws += 8192L * 1024 * 2;     // x bf16
  short* wqkvb = (short*)ws; ws += 3072L * 1024 * 2;     // [Wq; Wk; Wv''=Wo*Wv]
  short* wob   = (short*)ws; ws += 1024L * 1024 * 2;     // Wo bf16
  short* wvT   = (short*)ws; ws += 1024L * 1024 * 2;     // Wv^T bf16 [d,e]
  short* qb    = (short*)ws; ws += 8192L * 1024 * 2;     // Q
  short* kb    = (short*)ws; ws += 8192L * 1024 * 2;     // K
  short* vT    = (short*)ws; ws += 8192L * 1024 * 2;     // V'^T per batch [b][e][s]
  short* Sc    = (short*)ws; ws += 4L * 2048 * 2048 * 2; // scores -> probs
  float* bvp   = (float*)ws; ws += 1024L * 4;            // bv' = Wo*bv

  dim3 b256(256);
  k_cvt<<<8192, b256, 0, stream>>>(x, xb, 2097152);
  k_cvtw<<<dim3(1024, 3, 1), b256, 0, stream>>>(
      Wq, Wk, Wo, wqkvb, wqkvb + 1024L * 1024, wob);
  k_cvtT<<<dim3(64, 64, 1), b256, 0, stream>>>(Wv, wvT);
  // Wv'' = Wo*Wv = wob * wvT^T  -> third block of wqkvb
  k_gemm<0><<<dim3(8, 8, 1), b256, 0, stream>>>(
      wob, wvT, nullptr, nullptr, nullptr, wqkvb + 2048L * 1024, nullptr, nullptr,
      1024, 0, 0, 0, 1024);
  // bv' = Wo*bv (fp32 exact)
  k_matvec<<<256, b256, 0, stream>>>(Wo, bv, bvp);

  // fused QKV': [8192,3072] = x * [Wq;Wk;Wv'']^T, routed epilogue
  k_gemm<2><<<dim3(64, 24, 1), b256, 0, stream>>>(
      xb, wqkvb, bq, bk, bvp, qb, kb, vT, 1024, 0, 0, 0, 0);
  // scores[b] = Q[b]*K[b]^T
  k_gemm<0><<<dim3(16, 16, 4), b256, 0, stream>>>(
      qb, kb, nullptr, nullptr, nullptr, Sc, nullptr, nullptr,
      1024, 2048L * 1024, 2048L * 1024, 2048L * 2048, 2048);
  k_softmax<<<8192, b256, 0, stream>>>(Sc);
  // out = P * V' + bo -> fp32 d_out directly (out-projection eliminated)
  k_gemm<1><<<dim3(16, 8, 4), b256, 0, stream>>>(
      Sc, vT, bo, nullptr, nullptr, (float*)d_out, nullptr, nullptr,
      2048, 2048L * 2048, 1024L * 2048, 2048L * 1024, 1024);
}